// Round 2
// 387.005 us; speedup vs baseline: 1.0345x; 1.0345x over previous
//
#include <hip/hip_runtime.h>
#include <math.h>

#define B_TOT 4096
#define T_LEN 200
#define C_IN  16
#define HH    112
#define G4    448
#define NB    16      // batches per block (= MFMA M)
#define EPS   1e-5f
#define SBLK  256     // stats kernel blocks

typedef _Float16 half8  __attribute__((ext_vector_type(8)));
typedef float    f32x4  __attribute__((ext_vector_type(4)));

#define L2E 1.4426950408889634f

// Split fp32 into fp16 hi + 2^12-scaled fp16 lo. Flush hi if it would be a
// fp16 denormal (MFMA denormal behavior unverified); lo then carries the value.
__device__ __forceinline__ void split16(float v, _Float16 &hi, _Float16 &lo) {
    _Float16 h = (_Float16)v;
    float hf = (float)h;
    if (__builtin_fabsf(hf) < 6.103515625e-05f) { h = (_Float16)0.0f; hf = 0.0f; }
    hi = h;
    lo = (_Float16)((v - hf) * 4096.0f);
}

// ---------------- Kernel 1: deterministic per-channel partial sums ----------------
__global__ void stats_kernel(const float* __restrict__ x, float* __restrict__ ws) {
    __shared__ float sm[4][4][8];
    const int tid = threadIdx.x;
    const float4* __restrict__ x4 = (const float4*)x;
    const int total  = B_TOT * T_LEN * C_IN / 4;
    const int stride = SBLK * 256;
    const int i0 = blockIdx.x * 256 + tid;

    float s0=0.f,s1=0.f,s2=0.f,s3=0.f;
    float q0=0.f,q1=0.f,q2=0.f,q3=0.f;
    for (int i = i0; i < total; i += stride) {
        float4 v = x4[i];
        s0 += v.x; q0 += v.x*v.x;
        s1 += v.y; q1 += v.y*v.y;
        s2 += v.z; q2 += v.z*v.z;
        s3 += v.w; q3 += v.w*v.w;
    }
    #pragma unroll
    for (int off = 4; off < 64; off <<= 1) {
        s0 += __shfl_xor(s0, off); q0 += __shfl_xor(q0, off);
        s1 += __shfl_xor(s1, off); q1 += __shfl_xor(q1, off);
        s2 += __shfl_xor(s2, off); q2 += __shfl_xor(q2, off);
        s3 += __shfl_xor(s3, off); q3 += __shfl_xor(q3, off);
    }
    const int lane = tid & 63, wave = tid >> 6;
    if (lane < 4) {
        sm[wave][lane][0] = s0; sm[wave][lane][1] = s1;
        sm[wave][lane][2] = s2; sm[wave][lane][3] = s3;
        sm[wave][lane][4] = q0; sm[wave][lane][5] = q1;
        sm[wave][lane][6] = q2; sm[wave][lane][7] = q3;
    }
    __syncthreads();
    if (tid < 32) {
        const int ch = tid & 15, sq = tid >> 4;
        const int grp = ch >> 2, comp = ch & 3;
        float a = 0.f;
        #pragma unroll
        for (int wv = 0; wv < 4; wv++) a += sm[wv][grp][sq * 4 + comp];
        ws[blockIdx.x * 32 + tid] = a;
    }
}

// ---------------- Kernel 2: MFMA LSTM, one barrier/step ----------------
// 256 blocks x 448 threads (7 waves). Wave w owns the FOUR GATE TILES of
// j-tile w: n = gate*112 + 16w + nloc, gate = 0..3 (i,f,g,o). All four share
// the same D lane mapping -> cell update is in-lane, c in registers.
// v_t = [h_{t-1}; x_t] in LDS in A-fragment order, double-buffered by step parity.
//
// Inner loop is nt-OUTER so act[nt-1] VALU is independent of MFMA[nt] issue:
// the in-order wave fills MFMA pipe-stall slots with activation VALU instead of
// serializing a 48-MFMA burst then a VALU burst (was: 36% + 47% additive).

#define MFMA_NT(nt) do {                                                             \
    _Pragma("unroll")                                                                \
    for (int kt = 0; kt < 4; ++kt) {                                                 \
        ch[nt] = __builtin_amdgcn_mfma_f32_16x16x32_f16(ah[kt], wHI[nt][kt], ch[nt], 0, 0, 0); \
        cl[nt] = __builtin_amdgcn_mfma_f32_16x16x32_f16(al[kt], wHI[nt][kt], cl[nt], 0, 0, 0); \
        cl[nt] = __builtin_amdgcn_mfma_f32_16x16x32_f16(ah[kt], wLO[nt][kt], cl[nt], 0, 0, 0); \
    }                                                                                \
} while (0)

#define ACT_NT(nt) do {                                                              \
    const float mg_  = ((nt) == 2) ? 2.f : 1.f;                                      \
    const float k1_  = -mg_ * L2E;                                                   \
    const float k1s_ = k1_ * (1.f / 4096.f);                                         \
    const float dgc_ = 1.f - mg_;                                                    \
    _Pragma("unroll")                                                                \
    for (int r = 0; r < 4; ++r) {                                                    \
        float a_ = fmaf(ch[nt][r], k1_, bpre[nt]);                                   \
        a_ = fmaf(cl[nt][r], k1s_, a_);                                              \
        const float e_  = __builtin_amdgcn_exp2f(a_);                                \
        const float rr_ = __builtin_amdgcn_rcpf(1.f + e_);                           \
        act[nt][r] = fmaf(mg_, rr_, dgc_);                                           \
    }                                                                                \
} while (0)

__global__ __launch_bounds__(448, 2) void lstm_kernel(
    const float* __restrict__ x,
    const float* __restrict__ gamma, const float* __restrict__ beta,
    const float* __restrict__ W_ih,  const float* __restrict__ W_hh,
    const float* __restrict__ b_ih,  const float* __restrict__ b_hh,
    const float* __restrict__ W_fc,  const float* __restrict__ b_fc,
    const float* __restrict__ ws,    float* __restrict__ out)
{
    __shared__ float stats_s[32];
    __shared__ float scale_s[16], shift_s[16];
    __shared__ __align__(16) _Float16 vbuf[2][2][4][64][8]; // [plane][hi/lo][kt][lane][8]
    __shared__ __align__(16) float hfinal[NB][HH];

    const int u    = threadIdx.x;
    const int lane = u & 63;
    const int wv   = u >> 6;          // wave = j-tile 0..6
    const int nloc = lane & 15;
    const int q    = lane >> 4;       // 0..3
    const int b0   = blockIdx.x * NB;

    // --- BN stats (deterministic fixed-order reduction) ---
    if (u < 32) {
        float a = 0.f;
        for (int blk = 0; blk < SBLK; ++blk) a += ws[blk * 32 + u];
        stats_s[u] = a;
    }
    __syncthreads();
    if (u < 16) {
        const float N = (float)B_TOT * (float)T_LEN;
        const float mean = stats_s[u] / N;
        const float var  = stats_s[16 + u] / N - mean * mean;
        const float sc   = gamma[u] * rsqrtf(var + EPS);
        scale_s[u] = sc;
        shift_s[u] = beta[u] - mean * sc;
    }
    for (int i = u; i < (int)(sizeof(vbuf) / 4); i += G4) ((int*)vbuf)[i] = 0;
    __syncthreads();

    // --- Register-resident weight fragments (one-time) ---
    // B-fragment: lane (nloc,q) holds W_cat[n][k = kt*32 + q*8 + jj]
    half8 wHI[4][4], wLO[4][4];
    float bpre[4];                    // bias * k1 (activation-prescaled)
    #pragma unroll
    for (int nt = 0; nt < 4; ++nt) {  // nt == gate index
        const int n = nt * HH + wv * 16 + nloc;
        #pragma unroll
        for (int kt = 0; kt < 4; ++kt) {
            const int kb = kt * 32 + q * 8;    // never straddles k=112
            float wtmp[8];
            if (kb < HH) {
                float4 aa = *(const float4*)&W_hh[n * HH + kb];
                float4 bb = *(const float4*)&W_hh[n * HH + kb + 4];
                wtmp[0]=aa.x; wtmp[1]=aa.y; wtmp[2]=aa.z; wtmp[3]=aa.w;
                wtmp[4]=bb.x; wtmp[5]=bb.y; wtmp[6]=bb.z; wtmp[7]=bb.w;
            } else {
                const int c0 = kb - HH;
                float4 aa = *(const float4*)&W_ih[n * C_IN + c0];
                float4 bb = *(const float4*)&W_ih[n * C_IN + c0 + 4];
                wtmp[0]=aa.x*scale_s[c0+0]; wtmp[1]=aa.y*scale_s[c0+1];
                wtmp[2]=aa.z*scale_s[c0+2]; wtmp[3]=aa.w*scale_s[c0+3];
                wtmp[4]=bb.x*scale_s[c0+4]; wtmp[5]=bb.y*scale_s[c0+5];
                wtmp[6]=bb.z*scale_s[c0+6]; wtmp[7]=bb.w*scale_s[c0+7];
            }
            #pragma unroll
            for (int jj = 0; jj < 8; ++jj) {
                _Float16 th, tl;
                split16(wtmp[jj], th, tl);
                wHI[nt][kt][jj] = th;
                wLO[nt][kt][jj] = tl;
            }
        }
        float bb2 = b_ih[n] + b_hh[n];
        #pragma unroll
        for (int c = 0; c < C_IN; ++c) bb2 += W_ih[n * C_IN + c] * shift_s[c];
        const float mg = (nt == 2) ? 2.f : 1.f;
        bpre[nt] = bb2 * (-mg * L2E);
    }

    // --- h write-back mapping (A-fragment address for column jcol) ---
    const int jcol = wv * 16 + nloc;          // 0..111
    const int kt_h = jcol >> 5;
    const int jh   = jcol & 7;
    const int qh16 = ((jcol >> 3) & 3) * 16;  // lane' = b + qh16

    // --- x loader mapping: 256 threads (waves 0-3), ONE element each ---
    // (was: 35 extra ops concentrated on wave 0 -> barrier straggler)
    const int xb = u >> 4;                    // batch 0..15
    const int xc = u & 15;                    // channel 0..15
    const size_t xbase = (size_t)(b0 + xb) * (T_LEN * C_IN) + xc;
    const int ltx = xb + 16 * (((HH + xc) >> 3) & 3);   // A-frag lane for k=112+xc
    const int jx  = xc & 7;

    float xval;
    if (u < 256) {
        xval = x[xbase];                      // x at t=0 -> plane 0
        _Float16 xh, xl;
        split16(xval, xh, xl);
        vbuf[0][0][3][ltx][jx] = xh;
        vbuf[0][1][3][ltx][jx] = xl;
    }
    __syncthreads();

    float creg[4] = {0.f, 0.f, 0.f, 0.f};

    for (int step = 0; step < T_LEN; ++step) {
        const int p = step & 1;
        if (u < 256 && step + 1 < T_LEN)
            xval = x[xbase + (size_t)(step + 1) * C_IN];   // prefetch next x

        // A-fragments for this step (all 4 k-tiles, hi+lo planes)
        half8 ah[4], al[4];
        #pragma unroll
        for (int kt = 0; kt < 4; ++kt) {
            ah[kt] = *(const half8*)&vbuf[p][0][kt][lane][0];
            al[kt] = *(const half8*)&vbuf[p][1][kt][lane][0];
        }

        f32x4 ch[4], cl[4];
        #pragma unroll
        for (int nt = 0; nt < 4; ++nt) {
            ch[nt] = (f32x4){0.f, 0.f, 0.f, 0.f};
            cl[nt] = (f32x4){0.f, 0.f, 0.f, 0.f};
        }

        float act[4][4];
        float thc[4];

        // nt-outer pipeline: gate nt's activation VALU runs in the MFMA-issue
        // shadow of gate nt+1. Cell update needs act[0..2] so it slots into
        // gate-3's MFMA shadow, leaving only act[3]+h-write as serial tail.
        MFMA_NT(0);
        MFMA_NT(1);  ACT_NT(0);
        MFMA_NT(2);  ACT_NT(1);
        MFMA_NT(3);  ACT_NT(2);
        // cell update: depends only on act[0..2]; overlaps MFMA_NT(3) drain
        #pragma unroll
        for (int r = 0; r < 4; ++r) {
            const float cn = fmaf(act[1][r], creg[r], act[0][r] * act[2][r]);
            creg[r] = cn;
            const float e2 = __builtin_amdgcn_exp2f(cn * (-2.f * L2E));
            thc[r] = fmaf(2.f, __builtin_amdgcn_rcpf(1.f + e2), -1.f);
        }
        ACT_NT(3);

        const bool last = (step + 1 == T_LEN);
        #pragma unroll
        for (int r = 0; r < 4; ++r) {
            const float hv = act[3][r] * thc[r];
            if (!last) {
                _Float16 hh, hl;
                split16(hv, hh, hl);
                vbuf[1 - p][0][kt_h][q * 4 + r + qh16][jh] = hh;
                vbuf[1 - p][1][kt_h][q * 4 + r + qh16][jh] = hl;
            } else {
                hfinal[q * 4 + r][jcol] = hv;
            }
        }
        if (u < 256 && step + 1 < T_LEN) {
            _Float16 xh, xl;
            split16(xval, xh, xl);
            vbuf[1 - p][0][3][ltx][jx] = xh;
            vbuf[1 - p][1][3][ltx][jx] = xl;
        }
        __syncthreads();
    }

    // --- FC head ---
    if (u < NB * 6) {
        const int b = u / 6, o = u - b * 6;
        float a = b_fc[o];
        for (int j = 0; j < HH; ++j) a += hfinal[b][j] * W_fc[o * HH + j];
        out[(size_t)(b0 + b) * 6 + o] = tanhf(a);
    }
}

extern "C" void kernel_launch(void* const* d_in, const int* in_sizes, int n_in,
                              void* d_out, int out_size, void* d_ws, size_t ws_size,
                              hipStream_t stream) {
    const float* x     = (const float*)d_in[0];
    const float* gamma = (const float*)d_in[1];
    const float* beta  = (const float*)d_in[2];
    const float* W_ih  = (const float*)d_in[3];
    const float* W_hh  = (const float*)d_in[4];
    const float* b_ih  = (const float*)d_in[5];
    const float* b_hh  = (const float*)d_in[6];
    const float* W_fc  = (const float*)d_in[7];
    const float* b_fc  = (const float*)d_in[8];
    float* out = (float*)d_out;
    float* ws  = (float*)d_ws;

    stats_kernel<<<SBLK, 256, 0, stream>>>(x, ws);
    lstm_kernel<<<B_TOT / NB, 448, 0, stream>>>(x, gamma, beta, W_ih, W_hh,
                                                b_ih, b_hh, W_fc, b_fc, ws, out);
}

// Round 3
// 328.995 us; speedup vs baseline: 1.2169x; 1.1763x over previous
//
#include <hip/hip_runtime.h>
#include <math.h>

#define B_TOT 4096
#define T_LEN 200
#define C_IN  16
#define HH    112
#define G4    448
#define NB    16      // batches per block (= MFMA M)
#define EPS   1e-5f
#define SBLK  256     // stats kernel blocks

typedef _Float16 half8  __attribute__((ext_vector_type(8)));
typedef float    f32x4  __attribute__((ext_vector_type(4)));

#define L2E 1.4426950408889634f
#define FLUSH_MIN 6.103515625e-05f   // fp16 min normal

// Split fp32 into fp16 hi + 2^12-scaled fp16 lo (W-side only now).
__device__ __forceinline__ void split16(float v, _Float16 &hi, _Float16 &lo) {
    _Float16 h = (_Float16)v;
    float hf = (float)h;
    if (__builtin_fabsf(hf) < FLUSH_MIN) { h = (_Float16)0.0f; hf = 0.0f; }
    hi = h;
    lo = (_Float16)((v - hf) * 4096.0f);
}

// fp16 cast with denormal flush (A-side single-plane; error <= 6.1e-5 absolute).
__device__ __forceinline__ _Float16 to16(float v) {
    _Float16 h = (_Float16)v;
    if (__builtin_fabsf(v) < FLUSH_MIN) h = (_Float16)0.0f;
    return h;
}

// ---------------- Kernel 1: deterministic per-channel partial sums ----------------
__global__ void stats_kernel(const float* __restrict__ x, float* __restrict__ ws) {
    __shared__ float sm[4][4][8];
    const int tid = threadIdx.x;
    const float4* __restrict__ x4 = (const float4*)x;
    const int total  = B_TOT * T_LEN * C_IN / 4;
    const int stride = SBLK * 256;
    const int i0 = blockIdx.x * 256 + tid;

    float s0=0.f,s1=0.f,s2=0.f,s3=0.f;
    float q0=0.f,q1=0.f,q2=0.f,q3=0.f;
    for (int i = i0; i < total; i += stride) {
        float4 v = x4[i];
        s0 += v.x; q0 += v.x*v.x;
        s1 += v.y; q1 += v.y*v.y;
        s2 += v.z; q2 += v.z*v.z;
        s3 += v.w; q3 += v.w*v.w;
    }
    #pragma unroll
    for (int off = 4; off < 64; off <<= 1) {
        s0 += __shfl_xor(s0, off); q0 += __shfl_xor(q0, off);
        s1 += __shfl_xor(s1, off); q1 += __shfl_xor(q1, off);
        s2 += __shfl_xor(s2, off); q2 += __shfl_xor(q2, off);
        s3 += __shfl_xor(s3, off); q3 += __shfl_xor(q3, off);
    }
    const int lane = tid & 63, wave = tid >> 6;
    if (lane < 4) {
        sm[wave][lane][0] = s0; sm[wave][lane][1] = s1;
        sm[wave][lane][2] = s2; sm[wave][lane][3] = s3;
        sm[wave][lane][4] = q0; sm[wave][lane][5] = q1;
        sm[wave][lane][6] = q2; sm[wave][lane][7] = q3;
    }
    __syncthreads();
    if (tid < 32) {
        const int ch = tid & 15, sq = tid >> 4;
        const int grp = ch >> 2, comp = ch & 3;
        float a = 0.f;
        #pragma unroll
        for (int wv = 0; wv < 4; wv++) a += sm[wv][grp][sq * 4 + comp];
        ws[blockIdx.x * 32 + tid] = a;
    }
}

// ---------------- Kernel 2: MFMA LSTM, one barrier/step ----------------
// 256 blocks x 448 threads (7 waves). Wave w owns the FOUR GATE TILES of
// j-tile w: n = gate*112 + 16w + nloc. All four share the same D lane
// mapping -> cell update is in-lane, c in registers.
// v_t = [h_{t-1}; x_t] in LDS, A-fragment order, SINGLE fp16 plane
// (A-side lo plane dropped: h/x quantization injects <=1.2e-4/step noise,
// random-walk over 200 steps -> ~2-5e-4 at output; W keeps hi+lo since W
// quantization error would be systematic). 2 MFMAs per (gate,kt):
//   ch += ah*wHI   (main product, exact in h~fp16)
//   cl += ah*wLO   (W residual, scaled 2^12)
// -> 32 MFMAs/step/wave (was 48), cl chains 4-deep (was 8), half the
// ds_read/ds_write LDS traffic, no split16 on the per-step path.

#define MFMA_NT(nt) do {                                                             \
    _Pragma("unroll")                                                                \
    for (int kt = 0; kt < 4; ++kt) {                                                 \
        ch[nt] = __builtin_amdgcn_mfma_f32_16x16x32_f16(ah[kt], wHI[nt][kt], ch[nt], 0, 0, 0); \
        cl[nt] = __builtin_amdgcn_mfma_f32_16x16x32_f16(ah[kt], wLO[nt][kt], cl[nt], 0, 0, 0); \
    }                                                                                \
} while (0)

#define ACT_NT(nt) do {                                                              \
    const float mg_  = ((nt) == 2) ? 2.f : 1.f;                                      \
    const float k1_  = -mg_ * L2E;                                                   \
    const float k1s_ = k1_ * (1.f / 4096.f);                                         \
    const float dgc_ = 1.f - mg_;                                                    \
    _Pragma("unroll")                                                                \
    for (int r = 0; r < 4; ++r) {                                                    \
        float a_ = fmaf(ch[nt][r], k1_, bpre[nt]);                                   \
        a_ = fmaf(cl[nt][r], k1s_, a_);                                              \
        const float e_  = __builtin_amdgcn_exp2f(a_);                                \
        const float rr_ = __builtin_amdgcn_rcpf(1.f + e_);                           \
        act[nt][r] = fmaf(mg_, rr_, dgc_);                                           \
    }                                                                                \
} while (0)

__global__ __launch_bounds__(448, 2) void lstm_kernel(
    const float* __restrict__ x,
    const float* __restrict__ gamma, const float* __restrict__ beta,
    const float* __restrict__ W_ih,  const float* __restrict__ W_hh,
    const float* __restrict__ b_ih,  const float* __restrict__ b_hh,
    const float* __restrict__ W_fc,  const float* __restrict__ b_fc,
    const float* __restrict__ ws,    float* __restrict__ out)
{
    __shared__ float stats_s[32];
    __shared__ float scale_s[16], shift_s[16];
    __shared__ __align__(16) _Float16 vbuf[2][4][64][8]; // [parity][kt][lane][8] (hi plane only)
    __shared__ __align__(16) float hfinal[NB][HH];

    const int u    = threadIdx.x;
    const int lane = u & 63;
    const int wv   = u >> 6;          // wave = j-tile 0..6
    const int nloc = lane & 15;
    const int q    = lane >> 4;       // 0..3
    const int b0   = blockIdx.x * NB;

    // --- BN stats (deterministic fixed-order reduction) ---
    if (u < 32) {
        float a = 0.f;
        for (int blk = 0; blk < SBLK; ++blk) a += ws[blk * 32 + u];
        stats_s[u] = a;
    }
    __syncthreads();
    if (u < 16) {
        const float N = (float)B_TOT * (float)T_LEN;
        const float mean = stats_s[u] / N;
        const float var  = stats_s[16 + u] / N - mean * mean;
        const float sc   = gamma[u] * rsqrtf(var + EPS);
        scale_s[u] = sc;
        shift_s[u] = beta[u] - mean * sc;
    }
    for (int i = u; i < (int)(sizeof(vbuf) / 4); i += G4) ((int*)vbuf)[i] = 0;
    __syncthreads();

    // --- Register-resident weight fragments (one-time) ---
    // B-fragment: lane (nloc,q) holds W_cat[n][k = kt*32 + q*8 + jj]
    half8 wHI[4][4], wLO[4][4];
    float bpre[4];                    // bias * k1 (activation-prescaled)
    #pragma unroll
    for (int nt = 0; nt < 4; ++nt) {  // nt == gate index
        const int n = nt * HH + wv * 16 + nloc;
        #pragma unroll
        for (int kt = 0; kt < 4; ++kt) {
            const int kb = kt * 32 + q * 8;    // never straddles k=112
            float wtmp[8];
            if (kb < HH) {
                float4 aa = *(const float4*)&W_hh[n * HH + kb];
                float4 bb = *(const float4*)&W_hh[n * HH + kb + 4];
                wtmp[0]=aa.x; wtmp[1]=aa.y; wtmp[2]=aa.z; wtmp[3]=aa.w;
                wtmp[4]=bb.x; wtmp[5]=bb.y; wtmp[6]=bb.z; wtmp[7]=bb.w;
            } else {
                const int c0 = kb - HH;
                float4 aa = *(const float4*)&W_ih[n * C_IN + c0];
                float4 bb = *(const float4*)&W_ih[n * C_IN + c0 + 4];
                wtmp[0]=aa.x*scale_s[c0+0]; wtmp[1]=aa.y*scale_s[c0+1];
                wtmp[2]=aa.z*scale_s[c0+2]; wtmp[3]=aa.w*scale_s[c0+3];
                wtmp[4]=bb.x*scale_s[c0+4]; wtmp[5]=bb.y*scale_s[c0+5];
                wtmp[6]=bb.z*scale_s[c0+6]; wtmp[7]=bb.w*scale_s[c0+7];
            }
            #pragma unroll
            for (int jj = 0; jj < 8; ++jj) {
                _Float16 th, tl;
                split16(wtmp[jj], th, tl);
                wHI[nt][kt][jj] = th;
                wLO[nt][kt][jj] = tl;
            }
        }
        float bb2 = b_ih[n] + b_hh[n];
        #pragma unroll
        for (int c = 0; c < C_IN; ++c) bb2 += W_ih[n * C_IN + c] * shift_s[c];
        const float mg = (nt == 2) ? 2.f : 1.f;
        bpre[nt] = bb2 * (-mg * L2E);
    }

    // --- h write-back mapping (A-fragment address for column jcol) ---
    const int jcol = wv * 16 + nloc;          // 0..111
    const int kt_h = jcol >> 5;
    const int jh   = jcol & 7;
    const int qh16 = ((jcol >> 3) & 3) * 16;  // lane' = b + qh16

    // --- x loader mapping: 256 threads (waves 0-3), ONE element each ---
    const int xb = u >> 4;                    // batch 0..15
    const int xc = u & 15;                    // channel 0..15
    const size_t xbase = (size_t)(b0 + xb) * (T_LEN * C_IN) + xc;
    const int ltx = xb + 16 * (((HH + xc) >> 3) & 3);   // A-frag lane for k=112+xc
    const int jx  = xc & 7;

    float xval;
    if (u < 256) {
        xval = x[xbase];                      // x at t=0 -> parity 0
        vbuf[0][3][ltx][jx] = to16(xval);
    }
    __syncthreads();

    float creg[4] = {0.f, 0.f, 0.f, 0.f};

    for (int step = 0; step < T_LEN; ++step) {
        const int p = step & 1;
        if (u < 256 && step + 1 < T_LEN)
            xval = x[xbase + (size_t)(step + 1) * C_IN];   // prefetch next x

        // A-fragments for this step (all 4 k-tiles, single plane)
        half8 ah[4];
        #pragma unroll
        for (int kt = 0; kt < 4; ++kt)
            ah[kt] = *(const half8*)&vbuf[p][kt][lane][0];

        f32x4 ch[4], cl[4];
        #pragma unroll
        for (int nt = 0; nt < 4; ++nt) {
            ch[nt] = (f32x4){0.f, 0.f, 0.f, 0.f};
            cl[nt] = (f32x4){0.f, 0.f, 0.f, 0.f};
        }

        float act[4][4];
        float thc[4];

        // nt-outer pipeline: gate nt's activation VALU overlaps gate nt+1's
        // MFMA issue; cell update (needs i,f,g) overlaps gate-o's MFMAs.
        MFMA_NT(0);
        MFMA_NT(1);  ACT_NT(0);
        MFMA_NT(2);  ACT_NT(1);
        MFMA_NT(3);  ACT_NT(2);
        #pragma unroll
        for (int r = 0; r < 4; ++r) {
            const float cn = fmaf(act[1][r], creg[r], act[0][r] * act[2][r]);
            creg[r] = cn;
            const float e2 = __builtin_amdgcn_exp2f(cn * (-2.f * L2E));
            thc[r] = fmaf(2.f, __builtin_amdgcn_rcpf(1.f + e2), -1.f);
        }
        ACT_NT(3);

        const bool last = (step + 1 == T_LEN);
        #pragma unroll
        for (int r = 0; r < 4; ++r) {
            const float hv = act[3][r] * thc[r];
            if (!last) {
                vbuf[1 - p][kt_h][q * 4 + r + qh16][jh] = to16(hv);
            } else {
                hfinal[q * 4 + r][jcol] = hv;
            }
        }
        if (u < 256 && step + 1 < T_LEN)
            vbuf[1 - p][3][ltx][jx] = to16(xval);
        __syncthreads();
    }

    // --- FC head ---
    if (u < NB * 6) {
        const int b = u / 6, o = u - b * 6;
        float a = b_fc[o];
        for (int j = 0; j < HH; ++j) a += hfinal[b][j] * W_fc[o * HH + j];
        out[(size_t)(b0 + b) * 6 + o] = tanhf(a);
    }
}

extern "C" void kernel_launch(void* const* d_in, const int* in_sizes, int n_in,
                              void* d_out, int out_size, void* d_ws, size_t ws_size,
                              hipStream_t stream) {
    const float* x     = (const float*)d_in[0];
    const float* gamma = (const float*)d_in[1];
    const float* beta  = (const float*)d_in[2];
    const float* W_ih  = (const float*)d_in[3];
    const float* W_hh  = (const float*)d_in[4];
    const float* b_ih  = (const float*)d_in[5];
    const float* b_hh  = (const float*)d_in[6];
    const float* W_fc  = (const float*)d_in[7];
    const float* b_fc  = (const float*)d_in[8];
    float* out = (float*)d_out;
    float* ws  = (float*)d_ws;

    stats_kernel<<<SBLK, 256, 0, stream>>>(x, ws);
    lstm_kernel<<<B_TOT / NB, 448, 0, stream>>>(x, gamma, beta, W_ih, W_hh,
                                                b_ih, b_hh, W_fc, b_fc, ws, out);
}